// Round 2
// baseline (112.858 us; speedup 1.0000x reference)
//
#include <hip/hip_runtime.h>
#include <hip/hip_bf16.h>
#include <math.h>

#define D 128
#define INV_TAU 5.0f

typedef short bf16x8 __attribute__((ext_vector_type(8)));
typedef unsigned short u16x8 __attribute__((ext_vector_type(8)));
typedef float f32x4 __attribute__((ext_vector_type(4)));

__device__ __forceinline__ unsigned short bf16_bits(float v) {
    __hip_bfloat16 hb = __float2bfloat16(v);
    return *(unsigned short*)&hb;
}

// ---------- K1: per-pair prep, 2 pairs per 256-thread block. Half-block h
// owns pair k = 2*blockIdx.x + h, i.e. row a = pp[2k] (rows covered exactly
// once since pairs are mirrored). Writes pos[a], hnn[a] (hard-neg, partner =
// largest index not in {a,b}), hpn[a] (hard-pos).
__global__ __launch_bounds__(256) void prep_pair_kernel(
        const float* __restrict__ emb, const int* __restrict__ pp,
        int* __restrict__ pos, unsigned short* __restrict__ hnn,
        float* __restrict__ hpn, float* __restrict__ out, int N, int K) {
    int tid = threadIdx.x;
    int half = tid >> 7;      // 0/1: which pair of this block
    int d = tid & 127;        // feature index
    int k = blockIdx.x * 2 + half;
    bool live = (k < K);
    int a = 0, b = 0;
    if (live) { a = pp[2 * k]; b = pp[2 * k + 1]; }
    if (k == 0 && d == 0) *out = 0.0f;
    if (live && d == 0) pos[a] = b;
    // partner = largest index not in {a, b}
    int p = N - 1;
    if (p == a || p == b) p = N - 2;
    if (p == a || p == b) p = N - 3;

    float ea = live ? emb[(size_t)a * D + d] : 0.0f;
    float eb = live ? emb[(size_t)b * D + d] : 0.0f;
    float ep = live ? emb[(size_t)p * D + d] : 0.0f;
    float hn = 0.5f * (ea + ep);
    float hp = 1.5f * ea - 0.5f * eb;

    float sn = hn * hn, sp = hp * hp;
#pragma unroll
    for (int off = 32; off > 0; off >>= 1) {
        sn += __shfl_down(sn, off);
        sp += __shfl_down(sp, off);
    }
    __shared__ float tn[4], tp[4];
    if ((tid & 63) == 0) { tn[tid >> 6] = sn; tp[tid >> 6] = sp; }
    __syncthreads();
    if (!live) return;
    float invn = 1.0f / fmaxf(sqrtf(tn[half * 2] + tn[half * 2 + 1]), 1e-8f);
    float invp = 1.0f / fmaxf(sqrtf(tp[half * 2] + tp[half * 2 + 1]), 1e-8f);
    hnn[(size_t)a * D + d] = bf16_bits(hn * invn);
    hpn[(size_t)a * D + d] = hp * invp;
}

// ---------- K2: 128x128-tile bf16 MFMA GEMM -> sortable-u16 sims ----------
// 256 thr = 4 waves; wave (rowhalf, colhalf) computes a 64x64 quadrant.
// LDS row stride 136 u16: frag ds_read_b128 <=2-way conflicts (free, m136).
// Epilogue: C-tile staged in As (LDS) -> fully-coalesced dwordx4 stores.
// Write-BW bound (~32 MB) — unchanged from V6 (known-good numerics).
__global__ __launch_bounds__(256) void gemm_sim(const unsigned short* __restrict__ hnn,
                                                const int* __restrict__ pos,
                                                unsigned short* __restrict__ sims, int N) {
    __shared__ unsigned short As[128 * 136];
    __shared__ unsigned short Bs[128 * 136];
    __shared__ int pos_s[128];
    int tid = threadIdx.x;
    int rowBase = blockIdx.y * 128, colBase = blockIdx.x * 128;
    if (tid < 128) pos_s[tid] = pos[rowBase + tid];

    u16x8 ra[8], rb[8];
#pragma unroll
    for (int i = 0; i < 8; ++i) {
        int idx = i * 256 + tid;
        int row = idx >> 4, seg = idx & 15;
        ra[i] = *(const u16x8*)&hnn[(size_t)(rowBase + row) * D + seg * 8];
        rb[i] = *(const u16x8*)&hnn[(size_t)(colBase + row) * D + seg * 8];
    }
#pragma unroll
    for (int i = 0; i < 8; ++i) {
        int idx = i * 256 + tid;
        int row = idx >> 4, seg = idx & 15;
        *(u16x8*)&As[row * 136 + seg * 8] = ra[i];
        *(u16x8*)&Bs[row * 136 + seg * 8] = rb[i];
    }
    __syncthreads();

    int wave = tid >> 6, lane = tid & 63;
    int quad = lane >> 4, l15 = lane & 15;
    int rowhalf = wave >> 1, colhalf = wave & 1;

    f32x4 acc[4][4] = {};
#pragma unroll
    for (int kk = 0; kk < 4; ++kk) {
        bf16x8 af[4], bf[4];
#pragma unroll
        for (int rt = 0; rt < 4; ++rt)
            af[rt] = *(const bf16x8*)&As[(rowhalf * 64 + rt * 16 + l15) * 136 + kk * 32 + quad * 8];
#pragma unroll
        for (int ct = 0; ct < 4; ++ct)
            bf[ct] = *(const bf16x8*)&Bs[(colhalf * 64 + ct * 16 + l15) * 136 + kk * 32 + quad * 8];
#pragma unroll
        for (int rt = 0; rt < 4; ++rt)
#pragma unroll
            for (int ct = 0; ct < 4; ++ct)
                acc[rt][ct] = __builtin_amdgcn_mfma_f32_16x16x32_bf16(af[rt], bf[ct],
                                                                     acc[rt][ct], 0, 0, 0);
    }
    __syncthreads();  // done reading As/Bs; reuse As as the C-tile

#pragma unroll
    for (int rt = 0; rt < 4; ++rt) {
#pragma unroll
        for (int rg = 0; rg < 4; ++rg) {
            int rloc = rowhalf * 64 + rt * 16 + quad * 4 + rg;
            int r = rowBase + rloc;
            int pr = pos_s[rloc];
#pragma unroll
            for (int ct = 0; ct < 4; ++ct) {
                int cloc = colhalf * 64 + ct * 16 + l15;
                int c = colBase + cloc;
                unsigned short u = bf16_bits(acc[rt][ct][rg]);
                unsigned short sv = (u & 0x8000u) ? (unsigned short)~u
                                                  : (unsigned short)(u | 0x8000u);
                if (c == r || c == pr) sv = 0x0080;  // sortable(-3.39e38) -> exp == 0
                As[rloc * 136 + cloc] = sv;
            }
        }
    }
    __syncthreads();

    // coalesced write-out: 8 x dwordx4 per thread (1 KB per wave-instr)
#pragma unroll
    for (int i = 0; i < 8; ++i) {
        int idx = i * 256 + tid;
        int row = idx >> 4, seg = idx & 15;
        *(u16x8*)&sims[(size_t)(rowBase + row) * N + colBase + seg * 8] =
            *(const u16x8*)&As[row * 136 + seg * 8];
    }
}

// ---------- K3: wave-per-row rank-select + exp-sum + per-row loss ----------
// 512 thr = 8 waves = 8 rows, FIXED mapping (no grid-stride — R8 spill lesson).
// Counting via __ballot + scalar popcount.
// Binary search: FULL 16 rounds, b=15..0 from T=0. (R0 lesson: the sortable
// encoding puts positive sims in [0x8000,0xBFFF], so the rank-q threshold
// usually has bit 15 set — an OR-bit search must start at bit 15; a
// "[0x4000,0xC000) window" is not an OR-prefix, it needs a carry.)
// Bit loop NOT unrolled: keeps code ~1.6 KB vs 24 KB (I-cache hedge).
// loss = sum_r log1p(s_r/p_r)/K.
__global__ __launch_bounds__(512) void select_loss_kernel(
    const unsigned short* __restrict__ sims, const int* __restrict__ stage,
    const float* __restrict__ hpn, const int* __restrict__ pos,
    float* __restrict__ out, int N, int K, int q) {
    int wave = threadIdx.x >> 6, lane = threadIdx.x & 63;
    int row = blockIdx.x * 8 + wave;

    // issue the hard-pos dot-product loads early: they hide under the sims
    // loads and the select rounds
    int pr = pos[row];
    float h0 = hpn[(size_t)row * D + lane];
    float h1 = hpn[(size_t)row * D + lane + 64];
    float g0 = hpn[(size_t)pr * D + lane];
    float g1 = hpn[(size_t)pr * D + lane + 64];

    const unsigned short* rp = sims + (size_t)row * N;
    unsigned s[64];
#pragma unroll
    for (int j = 0; j < 8; ++j) {
        u16x8 t = *(const u16x8*)&rp[j * 512 + lane * 8];
#pragma unroll
        for (int e = 0; e < 8; ++e) s[j * 8 + e] = (unsigned)(unsigned short)t[e];
    }

    unsigned T = 0;
    if (stage[0]) {
#pragma unroll 1
        for (int b = 15; b >= 0; --b) {
            unsigned cand = T | (1u << b);
            int cnt = 0;
#pragma unroll
            for (int i = 0; i < 64; ++i)
                cnt += (int)__popcll(__ballot(s[i] < cand));
            if (cnt <= q) T = cand;  // rank-q element is >= cand
        }
    }

    float sum = 0.0f;
#pragma unroll
    for (int i = 0; i < 64; ++i) {
        if (s[i] >= T) {
            unsigned raw = (s[i] & 0x8000u) ? (s[i] ^ 0x8000u) : (~s[i] & 0xFFFFu);
            sum += __expf(__uint_as_float(raw << 16) * INV_TAU);
        }
    }
#pragma unroll
    for (int off = 1; off < 64; off <<= 1) sum += __shfl_xor(sum, off);

    // per-row loss term: log1p(s_row / p_row), p_row = exp(5*dot(hpn[row],hpn[pos]))
    float dsum = h0 * g0 + h1 * g1;
#pragma unroll
    for (int off = 32; off > 0; off >>= 1) dsum += __shfl_down(dsum, off);
    __shared__ float red[8];
    if (lane == 0) {
        float p = __expf(dsum * INV_TAU);
        red[wave] = log1pf(sum / p);
    }
    __syncthreads();
    if (threadIdx.x == 0) {
        float tot = 0.0f;
#pragma unroll
        for (int w = 0; w < 8; ++w) tot += red[w];
        atomicAdd(out, tot / (float)K);
    }
}

extern "C" void kernel_launch(void* const* d_in, const int* in_sizes, int n_in,
                              void* d_out, int out_size, void* d_ws, size_t ws_size,
                              hipStream_t stream) {
    const float* emb = (const float*)d_in[0];
    const int* pp = (const int*)d_in[1];
    const int* stage = (const int*)d_in[2];
    int N = in_sizes[0] / D;  // 4096
    int K = in_sizes[1] / 2;  // 4096 pairs

    char* ws = (char*)d_ws;
    size_t offPos = 0;
    size_t offHnn = offPos + (size_t)N * 4;       // u16 N*D
    size_t offHpn = offHnn + (size_t)N * D * 2;   // fp32 N*D
    size_t offSims = offHpn + (size_t)N * D * 4;  // u16 N*N (32 MB)
    int* pos = (int*)(ws + offPos);
    unsigned short* hnn = (unsigned short*)(ws + offHnn);
    float* hpn = (float*)(ws + offHpn);
    unsigned short* sims = (unsigned short*)(ws + offSims);

    prep_pair_kernel<<<(K + 1) / 2, 256, 0, stream>>>(emb, pp, pos, hnn, hpn,
                                                      (float*)d_out, N, K);
    dim3 g(N / 128, N / 128);
    gemm_sim<<<g, 256, 0, stream>>>(hnn, pos, sims, N);
    int q = (int)(0.8 * (double)(N - 1));  // 3276 for N=4096
    select_loss_kernel<<<N / 8, 512, 0, stream>>>(sims, stage, hpn, pos,
                                                  (float*)d_out, N, K, q);
}

// Round 3
// 111.175 us; speedup vs baseline: 1.0151x; 1.0151x over previous
//
#include <hip/hip_runtime.h>
#include <hip/hip_bf16.h>
#include <math.h>

#define D 128
#define INV_TAU 5.0f

typedef short bf16x8 __attribute__((ext_vector_type(8)));
typedef unsigned short u16x8 __attribute__((ext_vector_type(8)));
typedef float f32x4 __attribute__((ext_vector_type(4)));

__device__ __forceinline__ unsigned short bf16_bits(float v) {
    __hip_bfloat16 hb = __float2bfloat16(v);
    return *(unsigned short*)&hb;
}

// ---------- K1: per-pair prep. Block k owns row a = pp[2k] (rows are covered
// exactly once since pairs are mirrored). Writes pos[a], hnn[a] (hard-neg,
// partner = largest index not in {a,b} — O(1) from mirrored-pair argmax
// reduction), hpn[a] (hard-pos). No pos-array dependency => no scatter kernel.
// NOTE (R2): this is the byte-identical revert to the 111.4 µs-measured
// config. R0's bundle (2-pair blocks, K3 de-unroll, early loads) measured
// +1.4 µs — reverted.
__global__ void prep_pair_kernel(const float* __restrict__ emb, const int* __restrict__ pp,
                                 int* __restrict__ pos, unsigned short* __restrict__ hnn,
                                 float* __restrict__ hpn, float* __restrict__ out,
                                 int N, int K) {
    int k = blockIdx.x, d = threadIdx.x;  // blockDim = 128
    int a = pp[2 * k], b = pp[2 * k + 1];
    if (k == 0 && d == 0) *out = 0.0f;
    if (d == 0) pos[a] = b;
    // partner = largest index not in {a, b}
    int p = N - 1;
    if (p == a || p == b) p = N - 2;
    if (p == a || p == b) p = N - 3;

    float ea = emb[(size_t)a * D + d];
    float hn = 0.5f * (ea + emb[(size_t)p * D + d]);
    float hp = 1.5f * ea - 0.5f * emb[(size_t)b * D + d];

    float sn = hn * hn, sp = hp * hp;
#pragma unroll
    for (int off = 32; off > 0; off >>= 1) {
        sn += __shfl_down(sn, off);
        sp += __shfl_down(sp, off);
    }
    __shared__ float tn[2], tp[2];
    if ((d & 63) == 0) { tn[d >> 6] = sn; tp[d >> 6] = sp; }
    __syncthreads();
    float invn = 1.0f / fmaxf(sqrtf(tn[0] + tn[1]), 1e-8f);
    float invp = 1.0f / fmaxf(sqrtf(tp[0] + tp[1]), 1e-8f);
    hnn[(size_t)a * D + d] = bf16_bits(hn * invn);
    hpn[(size_t)a * D + d] = hp * invp;
}

// ---------- K2: 128x128-tile bf16 MFMA GEMM -> sortable-u16 sims ----------
// 256 thr = 4 waves; wave (rowhalf, colhalf) computes a 64x64 quadrant.
// LDS row stride 136 u16: frag ds_read_b128 <=2-way conflicts (free, m136).
// Epilogue: C-tile staged in As (LDS) -> fully-coalesced dwordx4 stores.
// Write-BW bound (~32 MB @ ~6 TB/s ≈ 5.5 µs floor).
__global__ __launch_bounds__(256) void gemm_sim(const unsigned short* __restrict__ hnn,
                                                const int* __restrict__ pos,
                                                unsigned short* __restrict__ sims, int N) {
    __shared__ unsigned short As[128 * 136];
    __shared__ unsigned short Bs[128 * 136];
    __shared__ int pos_s[128];
    int tid = threadIdx.x;
    int rowBase = blockIdx.y * 128, colBase = blockIdx.x * 128;
    if (tid < 128) pos_s[tid] = pos[rowBase + tid];

    u16x8 ra[8], rb[8];
#pragma unroll
    for (int i = 0; i < 8; ++i) {
        int idx = i * 256 + tid;
        int row = idx >> 4, seg = idx & 15;
        ra[i] = *(const u16x8*)&hnn[(size_t)(rowBase + row) * D + seg * 8];
        rb[i] = *(const u16x8*)&hnn[(size_t)(colBase + row) * D + seg * 8];
    }
#pragma unroll
    for (int i = 0; i < 8; ++i) {
        int idx = i * 256 + tid;
        int row = idx >> 4, seg = idx & 15;
        *(u16x8*)&As[row * 136 + seg * 8] = ra[i];
        *(u16x8*)&Bs[row * 136 + seg * 8] = rb[i];
    }
    __syncthreads();

    int wave = tid >> 6, lane = tid & 63;
    int quad = lane >> 4, l15 = lane & 15;
    int rowhalf = wave >> 1, colhalf = wave & 1;

    f32x4 acc[4][4] = {};
#pragma unroll
    for (int kk = 0; kk < 4; ++kk) {
        bf16x8 af[4], bf[4];
#pragma unroll
        for (int rt = 0; rt < 4; ++rt)
            af[rt] = *(const bf16x8*)&As[(rowhalf * 64 + rt * 16 + l15) * 136 + kk * 32 + quad * 8];
#pragma unroll
        for (int ct = 0; ct < 4; ++ct)
            bf[ct] = *(const bf16x8*)&Bs[(colhalf * 64 + ct * 16 + l15) * 136 + kk * 32 + quad * 8];
#pragma unroll
        for (int rt = 0; rt < 4; ++rt)
#pragma unroll
            for (int ct = 0; ct < 4; ++ct)
                acc[rt][ct] = __builtin_amdgcn_mfma_f32_16x16x32_bf16(af[rt], bf[ct],
                                                                     acc[rt][ct], 0, 0, 0);
    }
    __syncthreads();  // done reading As/Bs; reuse As as the C-tile

#pragma unroll
    for (int rt = 0; rt < 4; ++rt) {
#pragma unroll
        for (int rg = 0; rg < 4; ++rg) {
            int rloc = rowhalf * 64 + rt * 16 + quad * 4 + rg;
            int r = rowBase + rloc;
            int pr = pos_s[rloc];
#pragma unroll
            for (int ct = 0; ct < 4; ++ct) {
                int cloc = colhalf * 64 + ct * 16 + l15;
                int c = colBase + cloc;
                unsigned short u = bf16_bits(acc[rt][ct][rg]);
                unsigned short sv = (u & 0x8000u) ? (unsigned short)~u
                                                  : (unsigned short)(u | 0x8000u);
                if (c == r || c == pr) sv = 0x0080;  // sortable(-3.39e38) -> exp == 0
                As[rloc * 136 + cloc] = sv;
            }
        }
    }
    __syncthreads();

    // coalesced write-out: 8 x dwordx4 per thread (1 KB per wave-instr)
#pragma unroll
    for (int i = 0; i < 8; ++i) {
        int idx = i * 256 + tid;
        int row = idx >> 4, seg = idx & 15;
        *(u16x8*)&sims[(size_t)(rowBase + row) * N + colBase + seg * 8] =
            *(const u16x8*)&As[row * 136 + seg * 8];
    }
}

// ---------- K3: wave-per-row rank-select + exp-sum + per-row loss ----------
// 512 thr = 8 waves = 8 rows, FIXED mapping (no grid-stride — R8 spill lesson).
// Counting via __ballot + scalar popcount. loss = sum_r log1p(s_r/p_r)/K.
// Full 16-round OR-bit search from T=0 (positive sims live in [0x8000,
// 0xBFFF] — bit 15 must be searchable). Fully unrolled: measured best.
__global__ __launch_bounds__(512) void select_loss_kernel(
    const unsigned short* __restrict__ sims, const int* __restrict__ stage,
    const float* __restrict__ hpn, const int* __restrict__ pos,
    float* __restrict__ out, int N, int K, int q) {
    int wave = threadIdx.x >> 6, lane = threadIdx.x & 63;
    int row = blockIdx.x * 8 + wave;
    const unsigned short* rp = sims + (size_t)row * N;

    unsigned s[64];
#pragma unroll
    for (int j = 0; j < 8; ++j) {
        u16x8 t = *(const u16x8*)&rp[j * 512 + lane * 8];
#pragma unroll
        for (int e = 0; e < 8; ++e) s[j * 8 + e] = (unsigned)(unsigned short)t[e];
    }

    unsigned T = 0;
    if (stage[0]) {
#pragma unroll
        for (int b = 15; b >= 0; --b) {
            unsigned cand = T | (1u << b);
            int cnt = 0;
#pragma unroll
            for (int i = 0; i < 64; ++i)
                cnt += (int)__popcll(__ballot(s[i] < cand));
            if (cnt <= q) T = cand;  // rank-q element is >= cand
        }
    }

    float sum = 0.0f;
#pragma unroll
    for (int i = 0; i < 64; ++i) {
        if (s[i] >= T) {
            unsigned raw = (s[i] & 0x8000u) ? (s[i] ^ 0x8000u) : (~s[i] & 0xFFFFu);
            sum += __expf(__uint_as_float(raw << 16) * INV_TAU);
        }
    }
#pragma unroll
    for (int off = 1; off < 64; off <<= 1) sum += __shfl_xor(sum, off);

    // per-row loss term: log1p(s_row / p_row), p_row = exp(5*dot(hpn[row],hpn[pos]))
    int pr = pos[row];
    float dsum = hpn[(size_t)row * D + lane] * hpn[(size_t)pr * D + lane] +
                 hpn[(size_t)row * D + lane + 64] * hpn[(size_t)pr * D + lane + 64];
#pragma unroll
    for (int off = 32; off > 0; off >>= 1) dsum += __shfl_down(dsum, off);
    __shared__ float red[8];
    if (lane == 0) {
        float p = __expf(dsum * INV_TAU);
        red[wave] = log1pf(sum / p);
    }
    __syncthreads();
    if (threadIdx.x == 0) {
        float tot = 0.0f;
#pragma unroll
        for (int w = 0; w < 8; ++w) tot += red[w];
        atomicAdd(out, tot / (float)K);
    }
}

extern "C" void kernel_launch(void* const* d_in, const int* in_sizes, int n_in,
                              void* d_out, int out_size, void* d_ws, size_t ws_size,
                              hipStream_t stream) {
    const float* emb = (const float*)d_in[0];
    const int* pp = (const int*)d_in[1];
    const int* stage = (const int*)d_in[2];
    int N = in_sizes[0] / D;  // 4096
    int K = in_sizes[1] / 2;  // 4096 pairs

    char* ws = (char*)d_ws;
    size_t offPos = 0;
    size_t offHnn = offPos + (size_t)N * 4;       // u16 N*D
    size_t offHpn = offHnn + (size_t)N * D * 2;   // fp32 N*D
    size_t offSims = offHpn + (size_t)N * D * 4;  // u16 N*N (32 MB)
    int* pos = (int*)(ws + offPos);
    unsigned short* hnn = (unsigned short*)(ws + offHnn);
    float* hpn = (float*)(ws + offHpn);
    unsigned short* sims = (unsigned short*)(ws + offSims);

    prep_pair_kernel<<<K, D, 0, stream>>>(emb, pp, pos, hnn, hpn, (float*)d_out, N, K);
    dim3 g(N / 128, N / 128);
    gemm_sim<<<g, 256, 0, stream>>>(hnn, pos, sims, N);
    int q = (int)(0.8 * (double)(N - 1));  // 3276 for N=4096
    select_loss_kernel<<<N / 8, 512, 0, stream>>>(sims, stage, hpn, pos,
                                                  (float*)d_out, N, K, q);
}